// Round 11
// baseline (825.534 us; speedup 1.0000x reference)
//
#include <hip/hip_runtime.h>
#include <hip/hip_bf16.h>

#define T_STEPS 128
#define L2E  1.44269504f   // log2(e)
#define L2E2 2.88539008f   // 2*log2(e)

typedef __attribute__((ext_vector_type(8))) short short8;
typedef __attribute__((ext_vector_type(4))) float f32x4;

// One wave = one 16-batch tile. Per step:
//   gates[16b x 128gu] = hprev[16 x 32] @ W_hh.T + x_t*W_ih.T + b   (MFMA)
// Cell (weights pre-scaled by log2e; 2*log2e for g-gate):
//   c' = [ef*c*(ei+1)(eg+1) + ei*(eg-1)(ef+1)] / [(ef+1)(ei+1)(eg+1)]
//   h  = eo*(ec-1) / [(eo+1)(ec+1)],  ec = exp2(2*log2e*c')
// Cell math on f32x4 (v_pk_*_f32); 4-way paired rcp for denc (overflow-safe:
// product <= 1.4e36), 2-way for denh. h carried hi/lo-split bf16 (2 MFMAs per
// gate block): recurrence quantization ~1e-5, absmax at harness floor 9.8e-4.
//
// REGISTER BUDGET (round 11): __launch_bounds__(256, 3) caps unified
// VGPR+AGPR at floor(512/3)=170. Round-10 ran at ~224-256 total -> only
// 2 waves/SIMD (Occupancy 22%, VALUBusy 83% with dependency-stall idle).
// Hot set is ~150-170 regs so 3 waves/SIMD should fit without hot spills.
// TRIPWIRE: round 4 showed cap=128 vs demand ~230 -> 9.3 GB scratch traffic.
// If WRITE_SIZE >> 10 MB this failed; revert to plain __launch_bounds__(256).
extern "C" __global__ void __launch_bounds__(256, 3)
lstm_mfma_kernel(const float* __restrict__ x,
                 const float* __restrict__ W_ih,
                 const float* __restrict__ W_hh,
                 const float* __restrict__ b_ih,
                 const float* __restrict__ b_hh,
                 const float* __restrict__ W_fc,
                 const float* __restrict__ b_fc,
                 float* __restrict__ out, int B)
{
    __shared__ unsigned int hhi[4][256];       // h_hi [16 phys rows][16 u32]
    __shared__ unsigned int hlo[4][256];       // h_lo

    const int widx = threadIdx.x >> 6;
    const int lane = threadIdx.x & 63;
    const int p    = lane & 15;      // tile column
    const int g4   = lane >> 4;      // quarter-wave 0..3
    const int btile = (blockIdx.x * 4 + widx) * 16;
    if (btile >= B) return;

    unsigned int* hh = &hhi[widx][0];
    unsigned int* hl = &hlo[widx][0];

    // zero h tiles (h0 = 0)
    #pragma unroll
    for (int q = 0; q < 4; ++q) { hh[q * 64 + lane] = 0u; hl[q * 64 + lane] = 0u; }

    // ---- per-lane constants: W_hh B-fragments (scaled, bf16 RTN), bias, W_ih
    short8 wfrag[8];
    float  biasv[8], wihv[8];
    #pragma unroll
    for (int m = 0; m < 8; ++m) {
        int gu = (m >> 1) * 32 + 2 * p + (m & 1);
        float scale = (m >> 1) == 2 ? L2E2 : L2E;   // g-gate feeds exp2(2g*log2e)
        biasv[m] = (b_ih[gu] + b_hh[gu]) * scale;
        wihv[m]  = W_ih[gu] * scale;
        const float* wr = W_hh + gu * 32 + g4 * 8;   // 8 consecutive k
        short8 w;
        #pragma unroll
        for (int e = 0; e < 8; ++e) {
            unsigned int bits = __float_as_uint(wr[e] * scale);
            bits = bits + 0x7FFFu + ((bits >> 16) & 1u);   // RTN to bf16
            w[e] = (short)(bits >> 16);
        }
        wfrag[m] = w;
    }

    __builtin_amdgcn_wave_barrier();   // LDS zero-writes ordered before loop reads

    const float* xrow = x + (size_t)(btile + g4 * 4) * T_STEPS;

    // physical row of logical row p for A-fragment reads (phi involution)
    const int pp = ((p & 3) << 2) | (p >> 2);
    const int rdoff = pp * 16 + g4 * 4;

    f32x4 cst4[2];   // c state per unit-half, 4 batch rows
    f32x4 hn4[2];
    cst4[0] = 0.0f; cst4[1] = 0.0f;

    for (int tb = 0; tb < T_STEPS; tb += 4) {
        f32x4 xq[4];
        #pragma unroll
        for (int r = 0; r < 4; ++r)
            xq[r] = *reinterpret_cast<const f32x4*>(xrow + r * T_STEPS + tb);

        #pragma unroll
        for (int s = 0; s < 4; ++s) {
            // gather this step's x across the 4 batch rows
            f32x4 xs;
            xs[0] = xq[0][s]; xs[1] = xq[1][s]; xs[2] = xq[2][s]; xs[3] = xq[3][s];

            // acc init = scaled bias + x*scaled W_ih (vector fma -> v_pk)
            f32x4 acc[8];
            #pragma unroll
            for (int m = 0; m < 8; ++m)
                acc[m] = xs * wihv[m] + biasv[m];

            // previous h as A-fragments: logical row p -> physical pp
            short8 ahi = *reinterpret_cast<short8*>(&hh[rdoff]);
            short8 alo = *reinterpret_cast<short8*>(&hl[rdoff]);

            #pragma unroll
            for (int m = 0; m < 8; ++m) {
                acc[m] = __builtin_amdgcn_mfma_f32_16x16x32_bf16(ahi, wfrag[m], acc[m], 0, 0, 0);
                acc[m] = __builtin_amdgcn_mfma_f32_16x16x32_bf16(alo, wfrag[m], acc[m], 0, 0, 0);
            }

            // ---- LSTM cell on f32x4 (all 4 batch rows of unit-half U)
            #define CELL4(U) {                                                  \
                f32x4 gi = acc[0 + (U)];                                        \
                f32x4 gf = acc[2 + (U)];                                        \
                f32x4 gg = acc[4 + (U)];                                        \
                f32x4 go = acc[6 + (U)];                                        \
                f32x4 ei, ef, eg, eo;                                           \
                ei[0] = __builtin_amdgcn_exp2f(gi[0]);                          \
                ei[1] = __builtin_amdgcn_exp2f(gi[1]);                          \
                ei[2] = __builtin_amdgcn_exp2f(gi[2]);                          \
                ei[3] = __builtin_amdgcn_exp2f(gi[3]);                          \
                ef[0] = __builtin_amdgcn_exp2f(gf[0]);                          \
                ef[1] = __builtin_amdgcn_exp2f(gf[1]);                          \
                ef[2] = __builtin_amdgcn_exp2f(gf[2]);                          \
                ef[3] = __builtin_amdgcn_exp2f(gf[3]);                          \
                eg[0] = __builtin_amdgcn_exp2f(gg[0]);                          \
                eg[1] = __builtin_amdgcn_exp2f(gg[1]);                          \
                eg[2] = __builtin_amdgcn_exp2f(gg[2]);                          \
                eg[3] = __builtin_amdgcn_exp2f(gg[3]);                          \
                eo[0] = __builtin_amdgcn_exp2f(go[0]);                          \
                eo[1] = __builtin_amdgcn_exp2f(go[1]);                          \
                eo[2] = __builtin_amdgcn_exp2f(go[2]);                          \
                eo[3] = __builtin_amdgcn_exp2f(go[3]);                          \
                f32x4 ef1 = ef + 1.0f, ei1 = ei + 1.0f, eg1 = eg + 1.0f;        \
                f32x4 P    = ei1 * eg1;                                         \
                f32x4 denc = P * ef1;                                           \
                f32x4 num  = (ef * cst4[U]) * P + (ei * (eg - 1.0f)) * ef1;     \
                /* 4-way paired rcp for denc (overflow-safe) */                 \
                float d01 = denc[0] * denc[1];                                  \
                float d23 = denc[2] * denc[3];                                  \
                float rcq = __builtin_amdgcn_rcpf(d01 * d23);                   \
                float r01 = d23 * rcq, r23 = d01 * rcq;                         \
                f32x4 rc4;                                                      \
                rc4[0] = denc[1] * r01; rc4[1] = denc[0] * r01;                 \
                rc4[2] = denc[3] * r23; rc4[3] = denc[2] * r23;                 \
                f32x4 cn = num * rc4;                                           \
                cst4[U] = cn;                                                   \
                f32x4 ec;                                                       \
                ec[0] = __builtin_amdgcn_exp2f(cn[0] * L2E2);                   \
                ec[1] = __builtin_amdgcn_exp2f(cn[1] * L2E2);                   \
                ec[2] = __builtin_amdgcn_exp2f(cn[2] * L2E2);                   \
                ec[3] = __builtin_amdgcn_exp2f(cn[3] * L2E2);                   \
                f32x4 denh = (eo + 1.0f) * (ec + 1.0f);                         \
                f32x4 numh = eo * (ec - 1.0f);                                  \
                /* 2-way paired rcp for denh (same envelope as prior rounds) */ \
                float rh0 = __builtin_amdgcn_rcpf(denh[0] * denh[1]);           \
                float rh1 = __builtin_amdgcn_rcpf(denh[2] * denh[3]);           \
                f32x4 rh4;                                                      \
                rh4[0] = denh[1] * rh0; rh4[1] = denh[0] * rh0;                 \
                rh4[2] = denh[3] * rh1; rh4[3] = denh[2] * rh1;                 \
                hn4[U] = numh * rh4; }
            CELL4(0)
            CELL4(1)
            #undef CELL4

            // bf16 truncation + residual (vector ops -> v_pk where possible)
            f32x4 tr0, tr1;
            tr0[0] = __uint_as_float(__float_as_uint(hn4[0][0]) & 0xFFFF0000u);
            tr0[1] = __uint_as_float(__float_as_uint(hn4[0][1]) & 0xFFFF0000u);
            tr0[2] = __uint_as_float(__float_as_uint(hn4[0][2]) & 0xFFFF0000u);
            tr0[3] = __uint_as_float(__float_as_uint(hn4[0][3]) & 0xFFFF0000u);
            tr1[0] = __uint_as_float(__float_as_uint(hn4[1][0]) & 0xFFFF0000u);
            tr1[1] = __uint_as_float(__float_as_uint(hn4[1][1]) & 0xFFFF0000u);
            tr1[2] = __uint_as_float(__float_as_uint(hn4[1][2]) & 0xFFFF0000u);
            tr1[3] = __uint_as_float(__float_as_uint(hn4[1][3]) & 0xFFFF0000u);
            f32x4 res0 = hn4[0] - tr0;
            f32x4 res1 = hn4[1] - tr1;

            // pack (u=0,u=1) bf16 high-halves into one u32 via v_perm_b32;
            // write logical row g4*4+R at PHYSICAL row 4*R+g4.
            #define PACKR(R) {                                                  \
                unsigned int hiw = __builtin_amdgcn_perm(                       \
                    __float_as_uint(hn4[1][R]), __float_as_uint(hn4[0][R]),     \
                    0x07060302u);                                               \
                unsigned int low = __builtin_amdgcn_perm(                       \
                    __float_as_uint(res1[R]), __float_as_uint(res0[R]),         \
                    0x07060302u);                                               \
                int wa = (4 * (R) + g4) * 16 + p;                               \
                hh[wa] = hiw;                                                   \
                hl[wa] = low; }
            PACKR(0)
            PACKR(1)
            PACKR(2)
            PACKR(3)
            #undef PACKR
            __builtin_amdgcn_wave_barrier();   // order writes before next reads
        }
    }

    // ---- FC head: out[b][o] = sum_j h[b][j]*W_fc[o][j] + b_fc[o]
    float wfc00 = W_fc[2 * p], wfc01 = W_fc[2 * p + 1];
    float wfc10 = W_fc[32 + 2 * p], wfc11 = W_fc[32 + 2 * p + 1];
    float bfc0 = b_fc[0], bfc1 = b_fc[1];
    #define FCR(R) {                                                            \
        float h0 = hn4[0][R];                                                   \
        float h1 = hn4[1][R];                                                   \
        float o0 = fmaf(h0, wfc00, h1 * wfc01);                                 \
        float o1 = fmaf(h0, wfc10, h1 * wfc11);                                 \
        _Pragma("unroll")                                                       \
        for (int mm = 8; mm >= 1; mm >>= 1) {                                   \
            o0 += __shfl_xor(o0, mm, 64);                                       \
            o1 += __shfl_xor(o1, mm, 64);                                       \
        }                                                                       \
        if (p == 0) {                                                           \
            size_t b = (size_t)(btile + g4 * 4 + (R));                          \
            out[b * 2 + 0] = o0 + bfc0;                                         \
            out[b * 2 + 1] = o1 + bfc1;                                         \
        } }
    FCR(0)
    FCR(1)
    FCR(2)
    FCR(3)
    #undef FCR
}

extern "C" void kernel_launch(void* const* d_in, const int* in_sizes, int n_in,
                              void* d_out, int out_size, void* d_ws, size_t ws_size,
                              hipStream_t stream) {
    const float* x    = (const float*)d_in[0];
    const float* W_ih = (const float*)d_in[1];
    const float* W_hh = (const float*)d_in[2];
    const float* b_ih = (const float*)d_in[3];
    const float* b_hh = (const float*)d_in[4];
    const float* W_fc = (const float*)d_in[5];
    const float* b_fc = (const float*)d_in[6];
    float* out = (float*)d_out;

    int B = in_sizes[0] / T_STEPS;
    int grid = (B + 63) / 64;   // 64 batch per block (4 waves x 16)
    hipLaunchKernelGGL(lstm_mfma_kernel, dim3(grid), dim3(256), 0, stream,
                       x, W_ih, W_hh, b_ih, b_hh, W_fc, b_fc, out, B);
}

// Round 12
// 644.124 us; speedup vs baseline: 1.2816x; 1.2816x over previous
//
#include <hip/hip_runtime.h>
#include <hip/hip_bf16.h>

#define T_STEPS 128
#define L2E  1.44269504f   // log2(e)
#define L2E2 2.88539008f   // 2*log2(e)

typedef __attribute__((ext_vector_type(8))) short short8;
typedef __attribute__((ext_vector_type(4))) float f32x4;

// One wave = one 16-batch tile. Per step:
//   gates[16b x 128gu] = hprev[16 x 32] @ W_hh.T + x_t*W_ih.T + b   (MFMA)
// Cell (weights pre-scaled by log2e; 2*log2e for g-gate):
//   c' = [ef*c*(ei+1)(eg+1) + ei*(eg-1)(ef+1)] / [(ef+1)(ei+1)(eg+1)]
//   h  = eo*(ec-1) / [(eo+1)(ec+1)],  ec = exp2(2*log2e*c')
// Cell math on f32x4 (v_pk_*_f32); 4-way paired rcp for denc (overflow-safe:
// elem <= ~4e3 in-distribution, product << 1e38), 2-way for denh (wider
// dynamic range via exp2(2c) — keep the proven envelope).
//
// ROUND 12: single-RNE-bf16 h recurrence (v_cvt_pk_bf16_f32), lo-residual
// pipeline removed. Rationale: absmax was pinned at the 9.77e-4 comparison
// floor in EVERY passing round incl. the f32-recurrence round-1 kernel, so
// the hi/lo split bought precision ~20x below the floor while costing
// 8 MFMA + 1 ds_read_b128 + 4 ds_write + ~24 VALU per step (~9% of issue).
// Predicted kernel-added error ~3e-4 rms -> total ~1.3e-3 < 2.617e-3.
//
// NOTE: plain __launch_bounds__(256). (256,4) and (256,3) both forced the
// unified VGPR/AGPR allocation below demand -> scratch spills (round 4:
// 9.3 GB FETCH @ cap 128; round 11: 1 GB @ cap 170). Do not re-add.
extern "C" __global__ void __launch_bounds__(256)
lstm_mfma_kernel(const float* __restrict__ x,
                 const float* __restrict__ W_ih,
                 const float* __restrict__ W_hh,
                 const float* __restrict__ b_ih,
                 const float* __restrict__ b_hh,
                 const float* __restrict__ W_fc,
                 const float* __restrict__ b_fc,
                 float* __restrict__ out, int B)
{
    __shared__ unsigned int hhi[4][256];       // h [16 phys rows][16 u32 bf16x2]

    const int widx = threadIdx.x >> 6;
    const int lane = threadIdx.x & 63;
    const int p    = lane & 15;      // tile column
    const int g4   = lane >> 4;      // quarter-wave 0..3
    const int btile = (blockIdx.x * 4 + widx) * 16;
    if (btile >= B) return;

    unsigned int* hh = &hhi[widx][0];

    // zero h tile (h0 = 0)
    #pragma unroll
    for (int q = 0; q < 4; ++q) hh[q * 64 + lane] = 0u;

    // ---- per-lane constants: W_hh B-fragments (scaled, bf16 RTN), bias, W_ih
    short8 wfrag[8];
    float  biasv[8], wihv[8];
    #pragma unroll
    for (int m = 0; m < 8; ++m) {
        int gu = (m >> 1) * 32 + 2 * p + (m & 1);
        float scale = (m >> 1) == 2 ? L2E2 : L2E;   // g-gate feeds exp2(2g*log2e)
        biasv[m] = (b_ih[gu] + b_hh[gu]) * scale;
        wihv[m]  = W_ih[gu] * scale;
        const float* wr = W_hh + gu * 32 + g4 * 8;   // 8 consecutive k
        short8 w;
        #pragma unroll
        for (int e = 0; e < 8; ++e) {
            unsigned int bits = __float_as_uint(wr[e] * scale);
            bits = bits + 0x7FFFu + ((bits >> 16) & 1u);   // RTN to bf16
            w[e] = (short)(bits >> 16);
        }
        wfrag[m] = w;
    }

    __builtin_amdgcn_wave_barrier();   // LDS zero-writes ordered before loop reads

    const float* xrow = x + (size_t)(btile + g4 * 4) * T_STEPS;

    // physical row of logical row p for A-fragment reads (phi involution)
    const int pp = ((p & 3) << 2) | (p >> 2);
    const int rdoff = pp * 16 + g4 * 4;

    f32x4 cst4[2];   // c state per unit-half, 4 batch rows
    f32x4 hn4[2];
    cst4[0] = 0.0f; cst4[1] = 0.0f;

    for (int tb = 0; tb < T_STEPS; tb += 4) {
        f32x4 xq[4];
        #pragma unroll
        for (int r = 0; r < 4; ++r)
            xq[r] = *reinterpret_cast<const f32x4*>(xrow + r * T_STEPS + tb);

        #pragma unroll
        for (int s = 0; s < 4; ++s) {
            // gather this step's x across the 4 batch rows
            f32x4 xs;
            xs[0] = xq[0][s]; xs[1] = xq[1][s]; xs[2] = xq[2][s]; xs[3] = xq[3][s];

            // acc init = scaled bias + x*scaled W_ih (vector fma -> v_pk)
            f32x4 acc[8];
            #pragma unroll
            for (int m = 0; m < 8; ++m)
                acc[m] = xs * wihv[m] + biasv[m];

            // previous h as A-fragment: logical row p -> physical pp
            short8 ah = *reinterpret_cast<short8*>(&hh[rdoff]);

            #pragma unroll
            for (int m = 0; m < 8; ++m)
                acc[m] = __builtin_amdgcn_mfma_f32_16x16x32_bf16(ah, wfrag[m], acc[m], 0, 0, 0);

            // ---- LSTM cell on f32x4 (all 4 batch rows of unit-half U)
            #define CELL4(U) {                                                  \
                f32x4 gi = acc[0 + (U)];                                        \
                f32x4 gf = acc[2 + (U)];                                        \
                f32x4 gg = acc[4 + (U)];                                        \
                f32x4 go = acc[6 + (U)];                                        \
                f32x4 ei, ef, eg, eo;                                           \
                ei[0] = __builtin_amdgcn_exp2f(gi[0]);                          \
                ei[1] = __builtin_amdgcn_exp2f(gi[1]);                          \
                ei[2] = __builtin_amdgcn_exp2f(gi[2]);                          \
                ei[3] = __builtin_amdgcn_exp2f(gi[3]);                          \
                ef[0] = __builtin_amdgcn_exp2f(gf[0]);                          \
                ef[1] = __builtin_amdgcn_exp2f(gf[1]);                          \
                ef[2] = __builtin_amdgcn_exp2f(gf[2]);                          \
                ef[3] = __builtin_amdgcn_exp2f(gf[3]);                          \
                eg[0] = __builtin_amdgcn_exp2f(gg[0]);                          \
                eg[1] = __builtin_amdgcn_exp2f(gg[1]);                          \
                eg[2] = __builtin_amdgcn_exp2f(gg[2]);                          \
                eg[3] = __builtin_amdgcn_exp2f(gg[3]);                          \
                eo[0] = __builtin_amdgcn_exp2f(go[0]);                          \
                eo[1] = __builtin_amdgcn_exp2f(go[1]);                          \
                eo[2] = __builtin_amdgcn_exp2f(go[2]);                          \
                eo[3] = __builtin_amdgcn_exp2f(go[3]);                          \
                f32x4 ef1 = ef + 1.0f, ei1 = ei + 1.0f, eg1 = eg + 1.0f;        \
                f32x4 P    = ei1 * eg1;                                         \
                f32x4 denc = P * ef1;                                           \
                f32x4 num  = (ef * cst4[U]) * P + (ei * (eg - 1.0f)) * ef1;     \
                /* 4-way paired rcp for denc (overflow-safe) */                 \
                float d01 = denc[0] * denc[1];                                  \
                float d23 = denc[2] * denc[3];                                  \
                float rcq = __builtin_amdgcn_rcpf(d01 * d23);                   \
                float r01 = d23 * rcq, r23 = d01 * rcq;                         \
                f32x4 rc4;                                                      \
                rc4[0] = denc[1] * r01; rc4[1] = denc[0] * r01;                 \
                rc4[2] = denc[3] * r23; rc4[3] = denc[2] * r23;                 \
                f32x4 cn = num * rc4;                                           \
                cst4[U] = cn;                                                   \
                f32x4 ec;                                                       \
                ec[0] = __builtin_amdgcn_exp2f(cn[0] * L2E2);                   \
                ec[1] = __builtin_amdgcn_exp2f(cn[1] * L2E2);                   \
                ec[2] = __builtin_amdgcn_exp2f(cn[2] * L2E2);                   \
                ec[3] = __builtin_amdgcn_exp2f(cn[3] * L2E2);                   \
                f32x4 denh = (eo + 1.0f) * (ec + 1.0f);                         \
                f32x4 numh = eo * (ec - 1.0f);                                  \
                /* 2-way paired rcp for denh (proven envelope) */               \
                float rh0 = __builtin_amdgcn_rcpf(denh[0] * denh[1]);           \
                float rh1 = __builtin_amdgcn_rcpf(denh[2] * denh[3]);           \
                f32x4 rh4;                                                      \
                rh4[0] = denh[1] * rh0; rh4[1] = denh[0] * rh0;                 \
                rh4[2] = denh[3] * rh1; rh4[3] = denh[2] * rh1;                 \
                hn4[U] = numh * rh4; }
            CELL4(0)
            CELL4(1)
            #undef CELL4

            // pack h (u0,u1) -> one bf16x2 word, RNE, single instruction;
            // write logical row g4*4+R at PHYSICAL row 4*R+g4 (phi layout).
            #define PACKR(R) {                                                  \
                unsigned int w_;                                                \
                asm("v_cvt_pk_bf16_f32 %0, %1, %2"                              \
                    : "=v"(w_) : "v"(hn4[0][R]), "v"(hn4[1][R]));               \
                hh[(4 * (R) + g4) * 16 + p] = w_; }
            PACKR(0)
            PACKR(1)
            PACKR(2)
            PACKR(3)
            #undef PACKR
            __builtin_amdgcn_wave_barrier();   // order writes before next reads
        }
    }

    // ---- FC head: out[b][o] = sum_j h[b][j]*W_fc[o][j] + b_fc[o]
    float wfc00 = W_fc[2 * p], wfc01 = W_fc[2 * p + 1];
    float wfc10 = W_fc[32 + 2 * p], wfc11 = W_fc[32 + 2 * p + 1];
    float bfc0 = b_fc[0], bfc1 = b_fc[1];
    #define FCR(R) {                                                            \
        float h0 = hn4[0][R];                                                   \
        float h1 = hn4[1][R];                                                   \
        float o0 = fmaf(h0, wfc00, h1 * wfc01);                                 \
        float o1 = fmaf(h0, wfc10, h1 * wfc11);                                 \
        _Pragma("unroll")                                                       \
        for (int mm = 8; mm >= 1; mm >>= 1) {                                   \
            o0 += __shfl_xor(o0, mm, 64);                                       \
            o1 += __shfl_xor(o1, mm, 64);                                       \
        }                                                                       \
        if (p == 0) {                                                           \
            size_t b = (size_t)(btile + g4 * 4 + (R));                          \
            out[b * 2 + 0] = o0 + bfc0;                                         \
            out[b * 2 + 1] = o1 + bfc1;                                         \
        } }
    FCR(0)
    FCR(1)
    FCR(2)
    FCR(3)
    #undef FCR
}

extern "C" void kernel_launch(void* const* d_in, const int* in_sizes, int n_in,
                              void* d_out, int out_size, void* d_ws, size_t ws_size,
                              hipStream_t stream) {
    const float* x    = (const float*)d_in[0];
    const float* W_ih = (const float*)d_in[1];
    const float* W_hh = (const float*)d_in[2];
    const float* b_ih = (const float*)d_in[3];
    const float* b_hh = (const float*)d_in[4];
    const float* W_fc = (const float*)d_in[5];
    const float* b_fc = (const float*)d_in[6];
    float* out = (float*)d_out;

    int B = in_sizes[0] / T_STEPS;
    int grid = (B + 63) / 64;   // 64 batch per block (4 waves x 16)
    hipLaunchKernelGGL(lstm_mfma_kernel, dim3(grid), dim3(256), 0, stream,
                       x, W_ih, W_hh, b_ih, b_hh, W_fc, b_fc, out, B);
}